// Round 5
// baseline (33.228 us; speedup 1.0000x reference)
//
#include <hip/hip_runtime.h>
#include <math.h>

#define N_TOK 8192
#define DIM   4096
#define NEXP  8
#define TPW   4                 // tokens per wave-pair
#define HALF  (DIM / 2)         // each wave covers half of D
#define ITERS (HALF / 256)      // 8 iterations of 256 floats (lane*4)

// Block = 256 threads = 4 waves, 8 tokens per block:
//   wave (g,h): tokens [n0+g*4 .. n0+g*4+3], d-half h.
// Half-1 partials cross to half-0 waves via 256 B LDS; half-0 does epilogue.
//
// VMEM issue-order discipline (the R4 bug): vmcnt retires oldest-first, so
// anything needed at iter j must be OLDER in the queue than prefetches for
// j+1/j+2. Order per iter: [w(j+1)] [x(j+2)] [FMA(j) on w(j),x(j)] -> the
// compiler's counted wait (vmcnt(16)) leaves the deep x prefetch in flight.
__global__ __launch_bounds__(256) void router_kernel(
    const float* __restrict__ x,   // [N_TOK, DIM]
    const float* __restrict__ w,   // [NEXP, DIM]
    float* __restrict__ out)       // [N_TOK*8] combine ++ [N_TOK*2] idx-as-float
{
    __shared__ float red[2][TPW][NEXP];

    const int lane   = threadIdx.x & 63;
    const int waveid = threadIdx.x >> 6;   // 0..3
    const int g      = waveid >> 1;        // token group within block
    const int h      = waveid & 1;         // d-half
    const int n0     = blockIdx.x * 8 + g * TPW;

    float acc[TPW][NEXP];
    #pragma unroll
    for (int t = 0; t < TPW; ++t)
        #pragma unroll
        for (int e = 0; e < NEXP; ++e) acc[t][e] = 0.0f;

    const int dbase = h * HALF + lane * 4;
    const float* xr = x + (size_t)n0 * DIM + dbase;  // token t at xr + t*DIM
    const float* wr = w + dbase;                     // expert e at wr + e*DIM

    float4 xb[3][TPW];   // x: 3-slot rotation, prefetch distance 2
    float4 wb[2][NEXP];  // w: double buffer, prefetch distance 1

    // Prologue — strict age order: x(0), w(0), x(1)
    #pragma unroll
    for (int t = 0; t < TPW; ++t)
        xb[0][t] = *(const float4*)(xr + (size_t)t * DIM);
    #pragma unroll
    for (int e = 0; e < NEXP; ++e)
        wb[0][e] = *(const float4*)(wr + (size_t)e * DIM);
    #pragma unroll
    for (int t = 0; t < TPW; ++t)
        xb[1][t] = *(const float4*)(xr + (size_t)t * DIM + 256);

    #pragma unroll   // full unroll: all buffer indices compile-time constant
    for (int j = 0; j < ITERS; ++j) {
        if (j + 1 < ITERS) {                         // issue w(j+1) FIRST
            const int off = (j + 1) * 256;
            #pragma unroll
            for (int e = 0; e < NEXP; ++e)
                wb[(j + 1) & 1][e] = *(const float4*)(wr + (size_t)e * DIM + off);
        }
        if (j + 2 < ITERS) {                         // then x(j+2)
            const int off = (j + 2) * 256;
            #pragma unroll
            for (int t = 0; t < TPW; ++t)
                xb[(j + 2) % 3][t] = *(const float4*)(xr + (size_t)t * DIM + off);
        }

        #pragma unroll                                // consume w(j), x(j)
        for (int t = 0; t < TPW; ++t) {
            const float4 xv = xb[j % 3][t];
            #pragma unroll
            for (int e = 0; e < NEXP; ++e) {
                const float4 wv = wb[j & 1][e];
                acc[t][e] = fmaf(xv.x, wv.x,
                            fmaf(xv.y, wv.y,
                            fmaf(xv.z, wv.z,
                            fmaf(xv.w, wv.w, acc[t][e]))));
            }
        }
    }

    // 64-lane butterfly: every lane ends with the half-D partial sum
    #pragma unroll
    for (int t = 0; t < TPW; ++t) {
        #pragma unroll
        for (int e = 0; e < NEXP; ++e) {
            float v = acc[t][e];
            #pragma unroll
            for (int off = 32; off >= 1; off >>= 1)
                v += __shfl_xor(v, off, 64);
            acc[t][e] = v;
        }
    }

    // half 1 -> LDS
    if (h == 1 && lane == 0) {
        #pragma unroll
        for (int t = 0; t < TPW; ++t) {
            *(float4*)&red[g][t][0] = make_float4(acc[t][0], acc[t][1], acc[t][2], acc[t][3]);
            *(float4*)&red[g][t][4] = make_float4(acc[t][4], acc[t][5], acc[t][6], acc[t][7]);
        }
    }
    __syncthreads();

    if (h == 0) {
        #pragma unroll
        for (int t = 0; t < TPW; ++t) {
            float4 r0 = *(const float4*)&red[g][t][0];   // broadcast reads
            float4 r1 = *(const float4*)&red[g][t][4];
            acc[t][0] += r0.x; acc[t][1] += r0.y; acc[t][2] += r0.z; acc[t][3] += r0.w;
            acc[t][4] += r1.x; acc[t][5] += r1.y; acc[t][6] += r1.z; acc[t][7] += r1.w;
        }

        #pragma unroll
        for (int t = 0; t < TPW; ++t) {
            // argmax: strict >, ascending scan => lowest index wins ties (lax.top_k)
            float m1 = acc[t][0]; int i1 = 0;
            #pragma unroll
            for (int e = 1; e < NEXP; ++e)
                if (acc[t][e] > m1) { m1 = acc[t][e]; i1 = e; }
            float m2 = -INFINITY; int i2 = 0;
            #pragma unroll
            for (int e = 0; e < NEXP; ++e)
                if (e != i1 && acc[t][e] > m2) { m2 = acc[t][e]; i2 = e; }

            // softmax denom cancels under top-2 renorm:
            // w1 = 1/(1+exp(l2-l1)), w2 = exp(l2-l1)/(1+exp(l2-l1))
            const float e2  = expf(m2 - m1);
            const float inv = 1.0f / (1.0f + e2);
            const float w1  = inv;
            const float w2  = e2 * inv;

            if (lane == 0) {
                const int n = n0 + t;
                float c[8];
                #pragma unroll
                for (int e = 0; e < 8; ++e)
                    c[e] = (e == i1) ? w1 : ((e == i2) ? w2 : 0.0f);
                float4* cp = (float4*)(out + (size_t)n * 8);
                cp[0] = make_float4(c[0], c[1], c[2], c[3]);
                cp[1] = make_float4(c[4], c[5], c[6], c[7]);
                float* ip = out + (size_t)N_TOK * 8 + (size_t)n * 2;
                ip[0] = (float)i1;
                ip[1] = (float)i2;
            }
        }
    }
}

extern "C" void kernel_launch(void* const* d_in, const int* in_sizes, int n_in,
                              void* d_out, int out_size, void* d_ws, size_t ws_size,
                              hipStream_t stream) {
    const float* x = (const float*)d_in[0];   // [8192, 4096] f32
    const float* w = (const float*)d_in[1];   // [8, 4096] f32
    float* out = (float*)d_out;

    dim3 grid(N_TOK / 8);   // 1024 blocks x 8 tokens
    dim3 block(256);
    hipLaunchKernelGGL(router_kernel, grid, block, 0, stream, x, w, out);
}

// Round 6
// 33.010 us; speedup vs baseline: 1.0066x; 1.0066x over previous
//
#include <hip/hip_runtime.h>
#include <math.h>

#define N_TOK 8192
#define DIM   4096
#define NEXP  8
#define TPW   4                 // tokens per wave
#define HALF  (DIM / 2)         // each wave covers one d-half
#define ITERS (HALF / 256)      // 8 iters of 256 floats (lane*4)
#define WS_NEED ((size_t)N_TOK * 2 * NEXP * sizeof(float))   // part[n][h][e]

// ---------------- K1: partial logits for one d-half ----------------
// Block = 256 thr = 4 waves, ALL on half h = blockIdx.x&1; 16 tokens/block.
// w-half staged to LDS (lgkmcnt domain) so vmcnt counts ONLY the x burst:
// each wave issues its entire 32KB x working set back-to-back after the
// staging barrier, then consumes it oldest-first with counted vmcnt waits.
__global__ __launch_bounds__(256) void router_part_kernel(
    const float* __restrict__ x,     // [N_TOK, DIM]
    const float* __restrict__ w,     // [NEXP, DIM]
    float* __restrict__ part)        // [N_TOK][2][NEXP]
{
    __shared__ float wl[NEXP][HALF];  // 64 KB

    const int tid  = threadIdx.x;
    const int lane = tid & 63;
    const int wid  = tid >> 6;            // 0..3
    const int h    = blockIdx.x & 1;      // d-half
    const int blk  = blockIdx.x >> 1;     // 0..511
    const int n0   = blk * 16 + wid * TPW;

    // ---- stage w-half -> LDS (16 loads + 16 ds_writes per thread) ----
    {
        const float* wsrc = w + h * HALF;
        #pragma unroll
        for (int e = 0; e < NEXP; ++e) {
            #pragma unroll
            for (int p = 0; p < 2; ++p) {
                const int pos = p * 1024 + tid * 4;
                const float4 v = *(const float4*)(wsrc + (size_t)e * DIM + pos);
                *(float4*)&wl[e][pos] = v;
            }
        }
    }
    __syncthreads();   // drains staging only; x burst issued AFTER this

    // ---- full x burst: 32 x dwordx4, oldest = iter 0 ----
    const float* xr = x + (size_t)n0 * DIM + h * HALF + lane * 4;
    float4 xq[ITERS][TPW];
    #pragma unroll
    for (int j = 0; j < ITERS; ++j)
        #pragma unroll
        for (int t = 0; t < TPW; ++t)
            xq[j][t] = *(const float4*)(xr + (size_t)t * DIM + j * 256);

    float acc[TPW][NEXP];
    #pragma unroll
    for (int t = 0; t < TPW; ++t)
        #pragma unroll
        for (int e = 0; e < NEXP; ++e) acc[t][e] = 0.0f;

    // ---- consume: w via ds_read (lgkmcnt), x via counted vmcnt ----
    #pragma unroll
    for (int j = 0; j < ITERS; ++j) {
        float4 wv[NEXP];
        #pragma unroll
        for (int e = 0; e < NEXP; ++e)
            wv[e] = *(const float4*)&wl[e][j * 256 + lane * 4];
        #pragma unroll
        for (int t = 0; t < TPW; ++t) {
            const float4 xv = xq[j][t];
            #pragma unroll
            for (int e = 0; e < NEXP; ++e) {
                acc[t][e] = fmaf(xv.x, wv[e].x,
                            fmaf(xv.y, wv[e].y,
                            fmaf(xv.z, wv[e].z,
                            fmaf(xv.w, wv[e].w, acc[t][e]))));
            }
        }
    }

    // 64-lane butterfly (same summation structure as prior rounds)
    #pragma unroll
    for (int t = 0; t < TPW; ++t) {
        #pragma unroll
        for (int e = 0; e < NEXP; ++e) {
            float v = acc[t][e];
            #pragma unroll
            for (int off = 32; off >= 1; off >>= 1)
                v += __shfl_xor(v, off, 64);
            acc[t][e] = v;
        }
    }

    if (lane == 0) {
        #pragma unroll
        for (int t = 0; t < TPW; ++t) {
            float* p = part + ((size_t)(n0 + t) * 2 + h) * NEXP;
            *(float4*)(p + 0) = make_float4(acc[t][0], acc[t][1], acc[t][2], acc[t][3]);
            *(float4*)(p + 4) = make_float4(acc[t][4], acc[t][5], acc[t][6], acc[t][7]);
        }
    }
}

// ---------------- K2: combine halves + top-2 + renorm ----------------
__global__ __launch_bounds__(256) void router_top2_kernel(
    const float* __restrict__ part,  // [N_TOK][2][NEXP]
    float* __restrict__ out)         // [N_TOK*8] combine ++ [N_TOK*2] idx
{
    const int n = blockIdx.x * 256 + threadIdx.x;
    const float4* p = (const float4*)(part + (size_t)n * 16);
    const float4 a = p[0], b = p[1];   // half 0
    const float4 c = p[2], d = p[3];   // half 1

    float l[NEXP];
    l[0] = a.x + c.x; l[1] = a.y + c.y; l[2] = a.z + c.z; l[3] = a.w + c.w;
    l[4] = b.x + d.x; l[5] = b.y + d.y; l[6] = b.z + d.z; l[7] = b.w + d.w;

    // argmax: strict >, ascending scan => lowest index wins ties (lax.top_k)
    float m1 = l[0]; int i1 = 0;
    #pragma unroll
    for (int e = 1; e < NEXP; ++e)
        if (l[e] > m1) { m1 = l[e]; i1 = e; }
    float m2 = -INFINITY; int i2 = 0;
    #pragma unroll
    for (int e = 0; e < NEXP; ++e)
        if (e != i1 && l[e] > m2) { m2 = l[e]; i2 = e; }

    // softmax denom cancels under top-2 renorm:
    // w1 = 1/(1+exp(l2-l1)), w2 = exp(l2-l1)/(1+exp(l2-l1))
    const float e2  = expf(m2 - m1);
    const float inv = 1.0f / (1.0f + e2);
    const float w1  = inv;
    const float w2  = e2 * inv;

    float cmb[8];
    #pragma unroll
    for (int e = 0; e < 8; ++e)
        cmb[e] = (e == i1) ? w1 : ((e == i2) ? w2 : 0.0f);
    float4* cp = (float4*)(out + (size_t)n * 8);
    cp[0] = make_float4(cmb[0], cmb[1], cmb[2], cmb[3]);
    cp[1] = make_float4(cmb[4], cmb[5], cmb[6], cmb[7]);
    float* ip = out + (size_t)N_TOK * 8 + (size_t)n * 2;
    ip[0] = (float)i1;
    ip[1] = (float)i2;
}

// ---------------- Fallback (R4 single-kernel) if ws too small ----------------
__global__ __launch_bounds__(256) void router_fallback_kernel(
    const float* __restrict__ x, const float* __restrict__ w,
    float* __restrict__ out)
{
    __shared__ float red[2][TPW][NEXP];
    const int lane = threadIdx.x & 63;
    const int wid  = threadIdx.x >> 6;
    const int g    = wid >> 1;
    const int h    = wid & 1;
    const int n0   = blockIdx.x * 8 + g * TPW;

    float acc[TPW][NEXP];
    #pragma unroll
    for (int t = 0; t < TPW; ++t)
        #pragma unroll
        for (int e = 0; e < NEXP; ++e) acc[t][e] = 0.0f;

    const int dbase = h * HALF + lane * 4;
    const float* xr = x + (size_t)n0 * DIM + dbase;
    const float* wr = w + dbase;

    float4 xb[3][TPW];
    #pragma unroll
    for (int t = 0; t < TPW; ++t) xb[0][t] = *(const float4*)(xr + (size_t)t * DIM);
    #pragma unroll
    for (int t = 0; t < TPW; ++t) xb[1][t] = *(const float4*)(xr + (size_t)t * DIM + 256);

    #pragma unroll
    for (int it = 0; it < ITERS; ++it) {
        if (it + 2 < ITERS) {
            const int off = (it + 2) * 256;
            #pragma unroll
            for (int t = 0; t < TPW; ++t)
                xb[(it + 2) % 3][t] = *(const float4*)(xr + (size_t)t * DIM + off);
        }
        float4 wv[NEXP];
        #pragma unroll
        for (int e = 0; e < NEXP; ++e)
            wv[e] = *(const float4*)(wr + (size_t)e * DIM + it * 256);
        #pragma unroll
        for (int t = 0; t < TPW; ++t) {
            const float4 xv = xb[it % 3][t];
            #pragma unroll
            for (int e = 0; e < NEXP; ++e)
                acc[t][e] = fmaf(xv.x, wv[e].x, fmaf(xv.y, wv[e].y,
                            fmaf(xv.z, wv[e].z, fmaf(xv.w, wv[e].w, acc[t][e]))));
        }
    }
    #pragma unroll
    for (int t = 0; t < TPW; ++t)
        #pragma unroll
        for (int e = 0; e < NEXP; ++e) {
            float v = acc[t][e];
            #pragma unroll
            for (int off = 32; off >= 1; off >>= 1) v += __shfl_xor(v, off, 64);
            acc[t][e] = v;
        }
    if (h == 1 && lane == 0) {
        #pragma unroll
        for (int t = 0; t < TPW; ++t) {
            *(float4*)&red[g][t][0] = make_float4(acc[t][0], acc[t][1], acc[t][2], acc[t][3]);
            *(float4*)&red[g][t][4] = make_float4(acc[t][4], acc[t][5], acc[t][6], acc[t][7]);
        }
    }
    __syncthreads();
    if (h == 0) {
        #pragma unroll
        for (int t = 0; t < TPW; ++t) {
            float4 r0 = *(const float4*)&red[g][t][0];
            float4 r1 = *(const float4*)&red[g][t][4];
            acc[t][0] += r0.x; acc[t][1] += r0.y; acc[t][2] += r0.z; acc[t][3] += r0.w;
            acc[t][4] += r1.x; acc[t][5] += r1.y; acc[t][6] += r1.z; acc[t][7] += r1.w;
        }
        #pragma unroll
        for (int t = 0; t < TPW; ++t) {
            float m1 = acc[t][0]; int i1 = 0;
            #pragma unroll
            for (int e = 1; e < NEXP; ++e)
                if (acc[t][e] > m1) { m1 = acc[t][e]; i1 = e; }
            float m2 = -INFINITY; int i2 = 0;
            #pragma unroll
            for (int e = 0; e < NEXP; ++e)
                if (e != i1 && acc[t][e] > m2) { m2 = acc[t][e]; i2 = e; }
            const float e2  = expf(m2 - m1);
            const float inv = 1.0f / (1.0f + e2);
            if (lane == 0) {
                const int n = n0 + t;
                float c[8];
                #pragma unroll
                for (int e = 0; e < 8; ++e)
                    c[e] = (e == i1) ? inv : ((e == i2) ? e2 * inv : 0.0f);
                float4* cp = (float4*)(out + (size_t)n * 8);
                cp[0] = make_float4(c[0], c[1], c[2], c[3]);
                cp[1] = make_float4(c[4], c[5], c[6], c[7]);
                float* ip = out + (size_t)N_TOK * 8 + (size_t)n * 2;
                ip[0] = (float)i1;
                ip[1] = (float)i2;
            }
        }
    }
}

extern "C" void kernel_launch(void* const* d_in, const int* in_sizes, int n_in,
                              void* d_out, int out_size, void* d_ws, size_t ws_size,
                              hipStream_t stream) {
    const float* x = (const float*)d_in[0];   // [8192, 4096] f32
    const float* w = (const float*)d_in[1];   // [8, 4096] f32
    float* out = (float*)d_out;

    if (ws_size >= WS_NEED) {
        float* part = (float*)d_ws;           // [N_TOK][2][NEXP], fully overwritten
        hipLaunchKernelGGL(router_part_kernel, dim3(1024), dim3(256), 0, stream,
                           x, w, part);
        hipLaunchKernelGGL(router_top2_kernel, dim3(N_TOK / 256), dim3(256), 0, stream,
                           part, out);
    } else {
        hipLaunchKernelGGL(router_fallback_kernel, dim3(N_TOK / 8), dim3(256), 0, stream,
                           x, w, out);
    }
}